// Round 11
// baseline (204.258 us; speedup 1.0000x reference)
//
#include <hip/hip_runtime.h>
#include <hip/hip_bf16.h>

typedef unsigned short u16;
typedef __attribute__((ext_vector_type(8))) short bf16x8;
typedef __attribute__((ext_vector_type(4))) float f32x4;

#define SEQ_L 4096
#define M_TOT 16384   // B*L

__device__ __forceinline__ float bf2f(u16 x) {
    unsigned u = ((unsigned)x) << 16;
    return __builtin_bit_cast(float, u);
}
__device__ __forceinline__ u16 f2bf(float f) {
    unsigned u = __builtin_bit_cast(unsigned, f);
    u += 0x7FFFu + ((u >> 16) & 1u);   // round-to-nearest-even
    return (u16)(u >> 16);
}
// packed f32x2 -> bf16x2 (RNE), single VALU inst on gfx950 (lo=src0, hi=src1).
__device__ __forceinline__ unsigned cvt_pk_bf16(float lo, float hi) {
    unsigned r;
    asm("v_cvt_pk_bf16_f32 %0, %1, %2" : "=v"(r) : "v"(lo), "v"(hi));
    return r;
}
// async 16B global->LDS (direct-to-LDS DMA; LDS dest = wave-uniform base + lane*16)
__device__ __forceinline__ void gload16(const u16* g, u16* l) {
    __builtin_amdgcn_global_load_lds(
        (const __attribute__((address_space(1))) unsigned int*)g,
        (__attribute__((address_space(3))) unsigned int*)l, 16, 0, 0);
}

// ---- prep_all: pack six fp32 inputs -> x bf16 | Wqkv,Wout -> bf16 | mask -> u64 bitmap ----
__global__ __launch_bounds__(256) void prep_all(
    const float* __restrict__ in0, const float* __restrict__ in1, const float* __restrict__ in2,
    const float* __restrict__ in3, const float* __restrict__ in4, const float* __restrict__ in5,
    const float* __restrict__ Wqkv, const float* __restrict__ Wout, const void* __restrict__ mask,
    u16* __restrict__ x, u16* __restrict__ Wqkv_bf, u16* __restrict__ Wout_bf,
    unsigned long long* __restrict__ bmap) {
    int id = blockIdx.x * 256 + threadIdx.x;
    if (id < 1572864) {
        const float* ins[6] = {in0, in1, in2, in3, in4, in5};
        int which = id >> 18, j = id & 262143;
        int m = j >> 4, c8 = j & 15;
        const float* sp = ins[which] + (size_t)m * 128 + c8 * 8;
        float4 a = *(const float4*)sp;
        float4 b = *(const float4*)(sp + 4);
        u16 t[8] = {f2bf(a.x), f2bf(a.y), f2bf(a.z), f2bf(a.w),
                    f2bf(b.x), f2bf(b.y), f2bf(b.z), f2bf(b.w)};
        *(uint4*)(x + (size_t)m * 768 + which * 128 + c8 * 8) = *(uint4*)t;
    } else if (id < 1572864 + 73728 + 8192) {
        int i = id - 1572864;
        const float* src = (i < 73728) ? Wqkv : Wout;
        u16* dst = (i < 73728) ? Wqkv_bf : Wout_bf;
        if (i >= 73728) i -= 73728;
        const float* sp = src + (size_t)i * 8;
        float4 a = *(const float4*)sp;
        float4 b = *(const float4*)(sp + 4);
        u16 t[8] = {f2bf(a.x), f2bf(a.y), f2bf(a.z), f2bf(a.w),
                    f2bf(b.x), f2bf(b.y), f2bf(b.z), f2bf(b.w)};
        *(uint4*)(dst + (size_t)i * 8) = *(uint4*)t;
    } else if (id < 1572864 + 73728 + 8192 + 4096) {
        int i = id - 1572864 - 73728 - 8192;   // wave-aligned: one wave = one mask row
        int bi = i >> 6, bj = i & 63;
        size_t e = (size_t)(bi * 64) * SEQ_L + (size_t)bj * 64;
        const unsigned char* p8 = (const unsigned char*)mask;
        unsigned w0 = *(const unsigned*)mask;   // [0][0],[0][1] always true -> fingerprint
        bool v;
        if (w0 == 0x01010101u || w0 == 0xFFFFFFFFu)      v = p8[e] != 0;
        else if (w0 == 0x3F803F80u || w0 == 0x3C003C00u) v = ((const u16*)mask)[e] != 0;
        else                                             v = ((const unsigned*)mask)[e] != 0;
        unsigned long long bits = __ballot(v);
        if ((i & 63) == 0) bmap[bi] = bits;
    }
}

// ---------------- QKV GEMM v4: 256x256 tile, 8 waves, deep-pipelined ----------------
// Grid (64,3) = 192 blocks, 1 block/CU, LDS 128 KB (2x dbuf of A 32K + B 32K).
// Per K-tile: { vmcnt(0); s_barrier; sched_barrier; stage tile T+1 (8 gload16,
// other parity buffer); compute tile T (64 MFMA/wave) }. The stage->await span
// is a full compute group (~whole K-tile of MFMA) -- deep prefetch cover.
// Race-safety: stages issue only after the barrier certifying all waves finished
// reading the target buffer (tile T-1); readers of T+1 start only after the next
// vmcnt(0)+barrier. Same sync idiom as the verified attn kernel.
// Fragment/staging algebra: the production-verified chunk-XOR scheme (0 bank
// conflicts measured), remapped to 8 waves.
__global__ __launch_bounds__(512, 2) void qkv_gemm(
    const u16* __restrict__ X, const u16* __restrict__ W, const float* __restrict__ bias,
    u16* __restrict__ qk, u16* __restrict__ vt) {
    __shared__ __align__(16) u16 Al[2][256 * 64];   // 64 KB
    __shared__ __align__(16) u16 Bl[2][256 * 64];   // 64 KB
    int m0 = blockIdx.x * 256, n0 = blockIdx.y * 256;
    int tid = threadIdx.x, lane = tid & 63, w = tid >> 6;   // w 0..7
    int wr = w >> 2, wc = w & 3;            // wave sub-tile: rows wr*128.., cols wc*64..
    int ln = lane & 15, quad = lane >> 4;
    int lr8 = lane >> 3, lc = lane & 7;
    f32x4 acc[8][4] = {};                   // 128 rows x 64 cols per wave

    // prologue: stage K-tile 0 into parity-0 buffers (4+4 gload16/thread)
    #pragma unroll
    for (int j = 0; j < 4; j++) {
        int r = j * 64 + w * 8 + lr8;
        gload16(X + (size_t)(m0 + r) * 768 + ((lc ^ (r & 7)) * 8),
                Al[0] + (j * 64 + w * 8) * 64 + lane * 8);
        gload16(W + (size_t)(n0 + r) * 768 + ((lc ^ (r & 7)) * 8),
                Bl[0] + (j * 64 + w * 8) * 64 + lane * 8);
    }

    for (int T = 0; T < 12; T++) {
        int pi = T & 1;
        __builtin_amdgcn_s_waitcnt(0x0F70);     // vmcnt(0): my tile-T stages retired
        __builtin_amdgcn_s_barrier();           // tile T fully in LDS; T-1 reads done
        __builtin_amdgcn_sched_barrier(0);      // no hoisting of LDS reads above
        if (T + 1 < 12) {                       // stage tile T+1 into other parity
            int kk = (T + 1) * 64;
            #pragma unroll
            for (int j = 0; j < 4; j++) {
                int r = j * 64 + w * 8 + lr8;
                gload16(X + (size_t)(m0 + r) * 768 + kk + ((lc ^ (r & 7)) * 8),
                        Al[pi ^ 1] + (j * 64 + w * 8) * 64 + lane * 8);
                gload16(W + (size_t)(n0 + r) * 768 + kk + ((lc ^ (r & 7)) * 8),
                        Bl[pi ^ 1] + (j * 64 + w * 8) * 64 + lane * 8);
            }
        }
        const u16* A = Al[pi];
        const u16* B = Bl[pi];
        __builtin_amdgcn_s_setprio(1);
        #pragma unroll
        for (int mh = 0; mh < 2; mh++)
            #pragma unroll
            for (int nh = 0; nh < 2; nh++) {
                bf16x8 af[4][2], bfr[2][2];
                #pragma unroll
                for (int mi = 0; mi < 4; mi++)
                    #pragma unroll
                    for (int ks = 0; ks < 2; ks++) {
                        int R = wr * 128 + mh * 64 + mi * 16 + ln;
                        af[mi][ks] = *(const bf16x8*)(A + R * 64 +
                                       (((4 * ks + quad) ^ (ln & 7)) * 8));
                    }
                #pragma unroll
                for (int ni = 0; ni < 2; ni++)
                    #pragma unroll
                    for (int ks = 0; ks < 2; ks++) {
                        int R = wc * 64 + nh * 32 + ni * 16 + ln;
                        bfr[ni][ks] = *(const bf16x8*)(B + R * 64 +
                                        (((4 * ks + quad) ^ (ln & 7)) * 8));
                    }
                #pragma unroll
                for (int mi = 0; mi < 4; mi++)
                    #pragma unroll
                    for (int ni = 0; ni < 2; ni++)
                        #pragma unroll
                        for (int ks = 0; ks < 2; ks++)
                            acc[mh * 4 + mi][nh * 2 + ni] =
                                __builtin_amdgcn_mfma_f32_16x16x32_bf16(
                                    af[mi][ks], bfr[ni][ks],
                                    acc[mh * 4 + mi][nh * 2 + ni], 0, 0, 0);
            }
        __builtin_amdgcn_s_setprio(0);
    }

    if (n0 < 512) {   // n0 in {0,256}: entire block writes qk
        #pragma unroll
        for (int mi8 = 0; mi8 < 8; mi8++) {
            int row0 = m0 + wr * 128 + mi8 * 16 + 4 * quad;
            #pragma unroll
            for (int ni4 = 0; ni4 < 4; ni4++) {
                int col = n0 + wc * 64 + ni4 * 16 + ln;
                float bv = bias[col];
                #pragma unroll
                for (int r = 0; r < 4; r++)
                    qk[(size_t)(row0 + r) * 512 + col] = f2bf(acc[mi8][ni4][r] + bv);
            }
        }
    } else {          // n0 == 512: entire block writes vt (transposed V)
        #pragma unroll
        for (int mi8 = 0; mi8 < 8; mi8++) {
            int row0 = m0 + wr * 128 + mi8 * 16 + 4 * quad;
            int b = row0 >> 12, seq = row0 & 4095;
            #pragma unroll
            for (int ni4 = 0; ni4 < 4; ni4++) {
                int col = n0 + wc * 64 + ni4 * 16 + ln;
                float bv = bias[col];
                int d = col - 512;
                u16 pk[4] = {f2bf(acc[mi8][ni4][0] + bv), f2bf(acc[mi8][ni4][1] + bv),
                             f2bf(acc[mi8][ni4][2] + bv), f2bf(acc[mi8][ni4][3] + bv)};
                *(ushort4*)(vt + ((size_t)(b * 2 + (d >> 7)) * 128 + (d & 127)) * SEQ_L + seq)
                    = *(ushort4*)pk;
            }
        }
    }
}

// ---- block-sparse flash attention, v3.1: r4-verified structure + cvt_pk P-pack ----
__global__ __launch_bounds__(256, 2) void attn_sparse(
    const u16* __restrict__ qk, const u16* __restrict__ vt,
    const unsigned long long* __restrict__ bmap, u16* __restrict__ attn_bf) {
    __shared__ __align__(16) u16 Ks[2][64 * 128];   // 32 KB (double-buffered)
    __shared__ __align__(16) u16 Vs[2][128 * 64];   // 32 KB (double-buffered)

    int lane = threadIdx.x & 63, w = threadIdx.x >> 6;
    int ln = lane & 15, quad = lane >> 4;
    int u = blockIdx.x >> 3, v = blockIdx.x & 7;
    int qi = (u < 32) ? (63 - u) : (u - 32);    // heavy qi dispatched first
    int b = v >> 1, ch = v & 1;
    int rowbase = b * SEQ_L + qi * 64 + w * 16; // quarter = wave id
    const float scale = 0.08838834764831845f;   // 1/sqrt(128)

    // Q fragments (B-operand): lane holds q-col ln, k=32s+8quad+j
    bf16x8 qf[4];
    {
        const u16* qp = qk + (size_t)(rowbase + ln) * 512 + ch * 128;
        #pragma unroll
        for (int s = 0; s < 4; s++) qf[s] = *(const bf16x8*)(qp + 32 * s + 8 * quad);
    }

    float m_st = -1e30f, l_st = 0.f;            // per-lane: q-row = ln
    f32x4 accO[8] = {};

    const u16* kbase0 = qk + (size_t)b * SEQ_L * 512 + 256 + ch * 128;
    const u16* vbase0 = vt + (size_t)(b * 2 + ch) * 128 * SEQ_L;
    unsigned long long bm = bmap[qi];           // tril: bits > qi are already 0

    // prologue: stage first key-block into buffer 0 (4+4 gload16 per thread)
    int kb = __ffsll(bm) - 1; bm &= bm - 1;
    {
        const u16* kp = kbase0 + (size_t)(kb * 64) * 512;
        const u16* vp = vbase0 + kb * 64;
        #pragma unroll
        for (int j = 0; j < 4; j++) {           // K: wave w stages rows w*16..w*16+15
            int kr = w * 16 + j * 4 + (lane >> 4);
            gload16(kp + (size_t)kr * 512 + (((lane & 15) ^ (kr & 7)) * 8),
                    Ks[0] + (w * 16 + j * 4) * 128 + lane * 8);
        }
        #pragma unroll
        for (int j = 0; j < 4; j++) {           // V^T: wave w stages d-rows w*32..w*32+31
            int d = w * 32 + j * 8 + (lane >> 3);
            gload16(vp + (size_t)d * SEQ_L + (((lane & 7) ^ (d & 7)) * 8),
                    Vs[0] + (w * 32 + j * 8) * 64 + lane * 8);
        }
    }

    int srcA = ln + ((quad & 1) << 5);          // source lanes for P-fragment build
    int srcB = srcA + 16;
    bool hi = (quad & 2) != 0;                  // selects t = 2h+1 vs 2h

    int bufc = 0;
    while (true) {
        // prefetch next key-block into the other buffer
        int nkb = -1;
        if (bm) {
            nkb = __ffsll(bm) - 1; bm &= bm - 1;
            const u16* kp = kbase0 + (size_t)(nkb * 64) * 512;
            const u16* vp = vbase0 + nkb * 64;
            u16* Kd = Ks[bufc ^ 1];
            u16* Vd = Vs[bufc ^ 1];
            #pragma unroll
            for (int j = 0; j < 4; j++) {
                int kr = w * 16 + j * 4 + (lane >> 4);
                gload16(kp + (size_t)kr * 512 + (((lane & 15) ^ (kr & 7)) * 8),
                        Kd + (w * 16 + j * 4) * 128 + lane * 8);
            }
            #pragma unroll
            for (int j = 0; j < 4; j++) {
                int d = w * 32 + j * 8 + (lane >> 3);
                gload16(vp + (size_t)d * SEQ_L + (((lane & 7) ^ (d & 7)) * 8),
                        Vd + (w * 32 + j * 8) * 64 + lane * 8);
            }
        }
        // counted wait: prefetch loads stay in flight; current-tile loads done
        if (nkb >= 0) __builtin_amdgcn_s_waitcnt(0x0F78);   // vmcnt(8)
        else          __builtin_amdgcn_s_waitcnt(0x0F70);   // vmcnt(0)
        __builtin_amdgcn_s_barrier();           // everyone's staging landed

        const u16* K = Ks[bufc];
        const u16* V = Vs[bufc];

        // S^T = K Q^T over 64 keys: D[m = key = t*16+4*quad+r][n = q = ln]
        f32x4 accS[4] = {};
        #pragma unroll
        for (int s = 0; s < 4; s++)
            #pragma unroll
            for (int t = 0; t < 4; t++) {
                bf16x8 kf = *(const bf16x8*)(K + (t * 16 + ln) * 128 +
                                             (((4 * s + quad) ^ (ln & 7)) * 8));
                accS[t] = __builtin_amdgcn_mfma_f32_16x16x32_bf16(kf, qf[s], accS[t], 0, 0, 0);
            }

        // in-register online softmax for q-row = ln
        float mx = fmaxf(fmaxf(fmaxf(accS[0][0], accS[0][1]), fmaxf(accS[0][2], accS[0][3])),
                         fmaxf(fmaxf(fmaxf(accS[1][0], accS[1][1]), fmaxf(accS[1][2], accS[1][3])),
                               fmaxf(fmaxf(fmaxf(accS[2][0], accS[2][1]), fmaxf(accS[2][2], accS[2][3])),
                                     fmaxf(fmaxf(accS[3][0], accS[3][1]), fmaxf(accS[3][2], accS[3][3])))));
        mx = fmaxf(mx, __shfl_xor(mx, 16, 64));
        mx = fmaxf(mx, __shfl_xor(mx, 32, 64));
        float nm = fmaxf(m_st, mx * scale);
        float alpha = __expf(m_st - nm);
        m_st = nm;

        float p[4][4];
        float rs = 0.f;
        #pragma unroll
        for (int t = 0; t < 4; t++)
            #pragma unroll
            for (int r = 0; r < 4; r++) {
                p[t][r] = __expf(accS[t][r] * scale - nm);
                rs += p[t][r];
            }
        rs += __shfl_xor(rs, 16, 64);
        rs += __shfl_xor(rs, 32, 64);
        l_st = l_st * alpha + rs;

        // pack P^T to bf16 pairs via v_cvt_pk_bf16_f32 (1 inst per pair)
        unsigned uA[4], uB[4];
        #pragma unroll
        for (int t = 0; t < 4; t++) {
            uA[t] = cvt_pk_bf16(p[t][0], p[t][1]);
            uB[t] = cvt_pk_bf16(p[t][2], p[t][3]);
        }

        // rescale accO by alpha (transposed to accO rows q = 4*quad+r)
        float al[4];
        #pragma unroll
        for (int r = 0; r < 4; r++) al[r] = __shfl(alpha, 4 * quad + r, 64);
        #pragma unroll
        for (int nt = 0; nt < 8; nt++)
            #pragma unroll
            for (int r = 0; r < 4; r++) accO[nt][r] *= al[r];

        // O += P V : build pf (A-op: lane holds P[q=ln][k=h*32+8*quad+j]) via shfl
        #pragma unroll
        for (int h = 0; h < 2; h++) {
            unsigned a0 = (unsigned)__shfl((int)uA[2 * h], srcA, 64);
            unsigned a1 = (unsigned)__shfl((int)uA[2 * h + 1], srcA, 64);
            unsigned b0 = (unsigned)__shfl((int)uB[2 * h], srcA, 64);
            unsigned b1 = (unsigned)__shfl((int)uB[2 * h + 1], srcA, 64);
            unsigned c0 = (unsigned)__shfl((int)uA[2 * h], srcB, 64);
            unsigned c1 = (unsigned)__shfl((int)uA[2 * h + 1], srcB, 64);
            unsigned d0 = (unsigned)__shfl((int)uB[2 * h], srcB, 64);
            unsigned d1 = (unsigned)__shfl((int)uB[2 * h + 1], srcB, 64);
            union { unsigned w4[4]; bf16x8 v; } pu;
            pu.w4[0] = hi ? a1 : a0;
            pu.w4[1] = hi ? b1 : b0;
            pu.w4[2] = hi ? c1 : c0;
            pu.w4[3] = hi ? d1 : d0;
            bf16x8 pf = pu.v;
            #pragma unroll
            for (int nt = 0; nt < 8; nt++) {
                bf16x8 vf = *(const bf16x8*)(V + (nt * 16 + ln) * 64 +
                                             (((4 * h + quad) ^ (ln & 7)) * 8));
                accO[nt] = __builtin_amdgcn_mfma_f32_16x16x32_bf16(pf, vf, accO[nt], 0, 0, 0);
            }
        }

        if (nkb < 0) break;
        __builtin_amdgcn_s_barrier();           // all reads of bufc done -> reusable
        bufc ^= 1;
    }

    // epilogue: attn_bf[row][ch*128 + col] = O / l  (l transposed to rows q=4*quad+r)
    float linv = 1.0f / fmaxf(l_st, 1e-20f);
    float inv[4];
    #pragma unroll
    for (int r = 0; r < 4; r++) inv[r] = __shfl(linv, 4 * quad + r, 64);
    #pragma unroll
    for (int nt = 0; nt < 8; nt++)
        #pragma unroll
        for (int r = 0; r < 4; r++)
            attn_bf[(size_t)(rowbase + 4 * quad + r) * 256 + ch * 128 + nt * 16 + ln]
                = f2bf(accO[nt][r] * inv[r]);
}

// ---------------- out projection, 128x128 tile (grid 128x2 = 256 blocks) ----------------
__global__ __launch_bounds__(256, 3) void out_gemm(
    const u16* __restrict__ A, const u16* __restrict__ W, const float* __restrict__ bias,
    float* __restrict__ out) {
    __shared__ __align__(16) u16 As[128 * 64];
    __shared__ __align__(16) u16 Bs[128 * 64];
    int m0 = blockIdx.x * 128, n0 = blockIdx.y * 128;
    int tid = threadIdx.x, lane = tid & 63, w = tid >> 6;
    int ln = lane & 15, quad = lane >> 4;
    int rw = (w >> 1) * 64, cw = (w & 1) * 64;
    int lr8 = lane >> 3, lc = lane & 7;
    f32x4 acc[4][4] = {};
    for (int kk = 0; kk < 256; kk += 64) {
        __syncthreads();
        #pragma unroll
        for (int j = 0; j < 4; j++) {
            int r0 = w * 32 + j * 8, r = r0 + lr8;
            gload16(A + (size_t)(m0 + r) * 256 + kk + ((lc ^ (r & 7)) * 8), As + r0 * 64 + lane * 8);
            gload16(W + (size_t)(n0 + r) * 256 + kk + ((lc ^ (r & 7)) * 8), Bs + r0 * 64 + lane * 8);
        }
        __syncthreads();
        #pragma unroll
        for (int s = 0; s < 2; s++) {
            bf16x8 af[4], bfr[4];
            #pragma unroll
            for (int i = 0; i < 4; i++) {
                int R = rw + i * 16 + ln;
                af[i] = *(const bf16x8*)(As + R * 64 + ((4 * s + quad) ^ (ln & 7)) * 8);
            }
            #pragma unroll
            for (int t = 0; t < 4; t++) {
                int R = cw + t * 16 + ln;
                bfr[t] = *(const bf16x8*)(Bs + R * 64 + ((4 * s + quad) ^ (ln & 7)) * 8);
            }
            #pragma unroll
            for (int i = 0; i < 4; i++)
                #pragma unroll
                for (int t = 0; t < 4; t++)
                    acc[i][t] = __builtin_amdgcn_mfma_f32_16x16x32_bf16(af[i], bfr[t], acc[i][t], 0, 0, 0);
        }
    }
    // epilogue: col halves are block-uniform (n0 in {0,128})
    const size_t half = (size_t)M_TOT * 128;
    #pragma unroll
    for (int i = 0; i < 4; i++) {
        int row0 = m0 + rw + i * 16 + 4 * quad;
        #pragma unroll
        for (int t = 0; t < 4; t++) {
            int col = n0 + cw + t * 16 + ln;
            float bv = bias[col];
            float* base = (col < 128) ? (out + col) : (out + half + (col - 128));
            #pragma unroll
            for (int r = 0; r < 4; r++)
                base[(size_t)(row0 + r) * 128] = acc[i][t][r] + bv;
        }
    }
}

extern "C" void kernel_launch(void* const* d_in, const int* in_sizes, int n_in,
                              void* d_out, int out_size, void* d_ws, size_t ws_size,
                              hipStream_t stream) {
    char* ws = (char*)d_ws;
    u16* x_bf    = (u16*)ws;                          // 16384*768  = 25.2 MB
    u16* qk_buf  = x_bf + (size_t)M_TOT * 768;        // 16384*512  = 16.8 MB
    u16* vt_buf  = qk_buf + (size_t)M_TOT * 512;      // 1024*4096  =  8.4 MB
    u16* attn_bf = vt_buf + (size_t)1024 * SEQ_L;     // 16384*256  =  8.4 MB
    u16* Wqkv_bf = attn_bf + (size_t)M_TOT * 256;     // 589824
    u16* Wout_bf = Wqkv_bf + 589824;                  // 65536
    unsigned long long* bmap = (unsigned long long*)(Wout_bf + 65536);   // 64 x u64

    hipLaunchKernelGGL(prep_all, dim3(6480), dim3(256), 0, stream,
                       (const float*)d_in[0], (const float*)d_in[1], (const float*)d_in[2],
                       (const float*)d_in[3], (const float*)d_in[4], (const float*)d_in[5],
                       (const float*)d_in[6], (const float*)d_in[8], d_in[10],
                       x_bf, Wqkv_bf, Wout_bf, bmap);
    hipLaunchKernelGGL(qkv_gemm, dim3(64, 3), dim3(512), 0, stream,
                       x_bf, Wqkv_bf, (const float*)d_in[7], qk_buf, vt_buf);
    hipLaunchKernelGGL(attn_sparse, dim3(512), dim3(256), 0, stream,
                       qk_buf, vt_buf, bmap, attn_bf);
    hipLaunchKernelGGL(out_gemm, dim3(128, 2), dim3(256), 0, stream,
                       attn_bf, Wout_bf, (const float*)d_in[9], (float*)d_out);
}

// Round 12
// 195.699 us; speedup vs baseline: 1.0437x; 1.0437x over previous
//
#include <hip/hip_runtime.h>
#include <hip/hip_bf16.h>

typedef unsigned short u16;
typedef __attribute__((ext_vector_type(8))) short bf16x8;
typedef __attribute__((ext_vector_type(4))) float f32x4;

#define SEQ_L 4096
#define M_TOT 16384   // B*L

__device__ __forceinline__ float bf2f(u16 x) {
    unsigned u = ((unsigned)x) << 16;
    return __builtin_bit_cast(float, u);
}
__device__ __forceinline__ u16 f2bf(float f) {
    unsigned u = __builtin_bit_cast(unsigned, f);
    u += 0x7FFFu + ((u >> 16) & 1u);   // round-to-nearest-even
    return (u16)(u >> 16);
}
// async 16B global->LDS (direct-to-LDS DMA; LDS dest = wave-uniform base + lane*16)
__device__ __forceinline__ void gload16(const u16* g, u16* l) {
    __builtin_amdgcn_global_load_lds(
        (const __attribute__((address_space(1))) unsigned int*)g,
        (__attribute__((address_space(3))) unsigned int*)l, 16, 0, 0);
}

// ---- prep_all: pack six fp32 inputs -> x bf16 | Wqkv,Wout -> bf16 | mask -> u64 bitmap ----
__global__ __launch_bounds__(256) void prep_all(
    const float* __restrict__ in0, const float* __restrict__ in1, const float* __restrict__ in2,
    const float* __restrict__ in3, const float* __restrict__ in4, const float* __restrict__ in5,
    const float* __restrict__ Wqkv, const float* __restrict__ Wout, const void* __restrict__ mask,
    u16* __restrict__ x, u16* __restrict__ Wqkv_bf, u16* __restrict__ Wout_bf,
    unsigned long long* __restrict__ bmap) {
    int id = blockIdx.x * 256 + threadIdx.x;
    if (id < 1572864) {
        const float* ins[6] = {in0, in1, in2, in3, in4, in5};
        int which = id >> 18, j = id & 262143;
        int m = j >> 4, c8 = j & 15;
        const float* sp = ins[which] + (size_t)m * 128 + c8 * 8;
        float4 a = *(const float4*)sp;
        float4 b = *(const float4*)(sp + 4);
        u16 t[8] = {f2bf(a.x), f2bf(a.y), f2bf(a.z), f2bf(a.w),
                    f2bf(b.x), f2bf(b.y), f2bf(b.z), f2bf(b.w)};
        *(uint4*)(x + (size_t)m * 768 + which * 128 + c8 * 8) = *(uint4*)t;
    } else if (id < 1572864 + 73728 + 8192) {
        int i = id - 1572864;
        const float* src = (i < 73728) ? Wqkv : Wout;
        u16* dst = (i < 73728) ? Wqkv_bf : Wout_bf;
        if (i >= 73728) i -= 73728;
        const float* sp = src + (size_t)i * 8;
        float4 a = *(const float4*)sp;
        float4 b = *(const float4*)(sp + 4);
        u16 t[8] = {f2bf(a.x), f2bf(a.y), f2bf(a.z), f2bf(a.w),
                    f2bf(b.x), f2bf(b.y), f2bf(b.z), f2bf(b.w)};
        *(uint4*)(dst + (size_t)i * 8) = *(uint4*)t;
    } else if (id < 1572864 + 73728 + 8192 + 4096) {
        int i = id - 1572864 - 73728 - 8192;   // wave-aligned: one wave = one mask row
        int bi = i >> 6, bj = i & 63;
        size_t e = (size_t)(bi * 64) * SEQ_L + (size_t)bj * 64;
        const unsigned char* p8 = (const unsigned char*)mask;
        unsigned w0 = *(const unsigned*)mask;   // [0][0],[0][1] always true -> fingerprint
        bool v;
        if (w0 == 0x01010101u || w0 == 0xFFFFFFFFu)      v = p8[e] != 0;
        else if (w0 == 0x3F803F80u || w0 == 0x3C003C00u) v = ((const u16*)mask)[e] != 0;
        else                                             v = ((const unsigned*)mask)[e] != 0;
        unsigned long long bits = __ballot(v);
        if ((i & 63) == 0) bmap[bi] = bits;
    }
}

// ---------------- QKV GEMM, 128x128 tile (grid 128x6 = 768 = 3 blocks/CU) ----------------
__global__ __launch_bounds__(256, 3) void qkv_gemm(
    const u16* __restrict__ X, const u16* __restrict__ W, const float* __restrict__ bias,
    u16* __restrict__ qk, u16* __restrict__ vt) {
    __shared__ __align__(16) u16 As[128 * 64];
    __shared__ __align__(16) u16 Bs[128 * 64];
    int m0 = blockIdx.x * 128, n0 = blockIdx.y * 128;
    int tid = threadIdx.x, lane = tid & 63, w = tid >> 6;
    int ln = lane & 15, quad = lane >> 4;
    int rw = (w >> 1) * 64, cw = (w & 1) * 64;
    int lr8 = lane >> 3, lc = lane & 7;
    f32x4 acc[4][4] = {};
    for (int kk = 0; kk < 768; kk += 64) {
        __syncthreads();
        #pragma unroll
        for (int j = 0; j < 4; j++) {
            int r0 = w * 32 + j * 8, r = r0 + lr8;
            gload16(X + (size_t)(m0 + r) * 768 + kk + ((lc ^ (r & 7)) * 8), As + r0 * 64 + lane * 8);
            gload16(W + (size_t)(n0 + r) * 768 + kk + ((lc ^ (r & 7)) * 8), Bs + r0 * 64 + lane * 8);
        }
        __syncthreads();
        #pragma unroll
        for (int s = 0; s < 2; s++) {
            bf16x8 af[4], bfr[4];
            #pragma unroll
            for (int i = 0; i < 4; i++) {
                int R = rw + i * 16 + ln;
                af[i] = *(const bf16x8*)(As + R * 64 + ((4 * s + quad) ^ (ln & 7)) * 8);
            }
            #pragma unroll
            for (int t = 0; t < 4; t++) {
                int R = cw + t * 16 + ln;
                bfr[t] = *(const bf16x8*)(Bs + R * 64 + ((4 * s + quad) ^ (ln & 7)) * 8);
            }
            #pragma unroll
            for (int i = 0; i < 4; i++)
                #pragma unroll
                for (int t = 0; t < 4; t++)
                    acc[i][t] = __builtin_amdgcn_mfma_f32_16x16x32_bf16(af[i], bfr[t], acc[i][t], 0, 0, 0);
        }
    }
    if (n0 < 512) {   // entire block writes qk (512 is 128-aligned -> uniform)
        #pragma unroll
        for (int i = 0; i < 4; i++) {
            int row0 = m0 + rw + i * 16 + 4 * quad;
            #pragma unroll
            for (int t = 0; t < 4; t++) {
                int col = n0 + cw + t * 16 + ln;
                float bv = bias[col];
                #pragma unroll
                for (int r = 0; r < 4; r++)
                    qk[(size_t)(row0 + r) * 512 + col] = f2bf(acc[i][t][r] + bv);
            }
        }
    } else {          // entire block writes vt (transposed V, per batch-channel)
        #pragma unroll
        for (int i = 0; i < 4; i++) {
            int row0 = m0 + rw + i * 16 + 4 * quad;
            int b = row0 >> 12, seq = row0 & 4095;
            #pragma unroll
            for (int t = 0; t < 4; t++) {
                int col = n0 + cw + t * 16 + ln;
                float bv = bias[col];
                int d = col - 512;
                u16 pk[4] = {f2bf(acc[i][t][0] + bv), f2bf(acc[i][t][1] + bv),
                             f2bf(acc[i][t][2] + bv), f2bf(acc[i][t][3] + bv)};
                *(ushort4*)(vt + ((size_t)(b * 2 + (d >> 7)) * 128 + (d & 127)) * SEQ_L + seq)
                    = *(ushort4*)pk;
            }
        }
    }
}

// ---- block-sparse flash attention, v3 (r4-verified best): swapped QK^T,
// in-register softmax, f2bf P-pack, K/V dbuf + counted vmcnt(8) prefetch ----
__global__ __launch_bounds__(256, 2) void attn_sparse(
    const u16* __restrict__ qk, const u16* __restrict__ vt,
    const unsigned long long* __restrict__ bmap, u16* __restrict__ attn_bf) {
    __shared__ __align__(16) u16 Ks[2][64 * 128];   // 32 KB (double-buffered)
    __shared__ __align__(16) u16 Vs[2][128 * 64];   // 32 KB (double-buffered)

    int lane = threadIdx.x & 63, w = threadIdx.x >> 6;
    int ln = lane & 15, quad = lane >> 4;
    int u = blockIdx.x >> 3, v = blockIdx.x & 7;
    int qi = (u < 32) ? (63 - u) : (u - 32);    // heavy qi dispatched first
    int b = v >> 1, ch = v & 1;
    int rowbase = b * SEQ_L + qi * 64 + w * 16; // quarter = wave id
    const float scale = 0.08838834764831845f;   // 1/sqrt(128)

    // Q fragments (B-operand): lane holds q-col ln, k=32s+8quad+j
    bf16x8 qf[4];
    {
        const u16* qp = qk + (size_t)(rowbase + ln) * 512 + ch * 128;
        #pragma unroll
        for (int s = 0; s < 4; s++) qf[s] = *(const bf16x8*)(qp + 32 * s + 8 * quad);
    }

    float m_st = -1e30f, l_st = 0.f;            // per-lane: q-row = ln
    f32x4 accO[8] = {};

    const u16* kbase0 = qk + (size_t)b * SEQ_L * 512 + 256 + ch * 128;
    const u16* vbase0 = vt + (size_t)(b * 2 + ch) * 128 * SEQ_L;
    unsigned long long bm = bmap[qi];           // tril: bits > qi are already 0

    // prologue: stage first key-block into buffer 0 (4+4 gload16 per thread)
    int kb = __ffsll(bm) - 1; bm &= bm - 1;
    {
        const u16* kp = kbase0 + (size_t)(kb * 64) * 512;
        const u16* vp = vbase0 + kb * 64;
        #pragma unroll
        for (int j = 0; j < 4; j++) {           // K: wave w stages rows w*16..w*16+15
            int kr = w * 16 + j * 4 + (lane >> 4);
            gload16(kp + (size_t)kr * 512 + (((lane & 15) ^ (kr & 7)) * 8),
                    Ks[0] + (w * 16 + j * 4) * 128 + lane * 8);
        }
        #pragma unroll
        for (int j = 0; j < 4; j++) {           // V^T: wave w stages d-rows w*32..w*32+31
            int d = w * 32 + j * 8 + (lane >> 3);
            gload16(vp + (size_t)d * SEQ_L + (((lane & 7) ^ (d & 7)) * 8),
                    Vs[0] + (w * 32 + j * 8) * 64 + lane * 8);
        }
    }

    int srcA = ln + ((quad & 1) << 5);          // source lanes for P-fragment build
    int srcB = srcA + 16;
    bool hi = (quad & 2) != 0;                  // selects t = 2h+1 vs 2h

    int bufc = 0;
    while (true) {
        // prefetch next key-block into the other buffer
        int nkb = -1;
        if (bm) {
            nkb = __ffsll(bm) - 1; bm &= bm - 1;
            const u16* kp = kbase0 + (size_t)(nkb * 64) * 512;
            const u16* vp = vbase0 + nkb * 64;
            u16* Kd = Ks[bufc ^ 1];
            u16* Vd = Vs[bufc ^ 1];
            #pragma unroll
            for (int j = 0; j < 4; j++) {
                int kr = w * 16 + j * 4 + (lane >> 4);
                gload16(kp + (size_t)kr * 512 + (((lane & 15) ^ (kr & 7)) * 8),
                        Kd + (w * 16 + j * 4) * 128 + lane * 8);
            }
            #pragma unroll
            for (int j = 0; j < 4; j++) {
                int d = w * 32 + j * 8 + (lane >> 3);
                gload16(vp + (size_t)d * SEQ_L + (((lane & 7) ^ (d & 7)) * 8),
                        Vd + (w * 32 + j * 8) * 64 + lane * 8);
            }
        }
        // counted wait: prefetch loads stay in flight; current-tile loads done
        if (nkb >= 0) __builtin_amdgcn_s_waitcnt(0x0F78);   // vmcnt(8)
        else          __builtin_amdgcn_s_waitcnt(0x0F70);   // vmcnt(0)
        __builtin_amdgcn_s_barrier();           // everyone's staging landed

        const u16* K = Ks[bufc];
        const u16* V = Vs[bufc];

        // S^T = K Q^T over 64 keys: D[m = key = t*16+4*quad+r][n = q = ln]
        f32x4 accS[4] = {};
        #pragma unroll
        for (int s = 0; s < 4; s++)
            #pragma unroll
            for (int t = 0; t < 4; t++) {
                bf16x8 kf = *(const bf16x8*)(K + (t * 16 + ln) * 128 +
                                             (((4 * s + quad) ^ (ln & 7)) * 8));
                accS[t] = __builtin_amdgcn_mfma_f32_16x16x32_bf16(kf, qf[s], accS[t], 0, 0, 0);
            }

        // in-register online softmax for q-row = ln
        float mx = fmaxf(fmaxf(fmaxf(accS[0][0], accS[0][1]), fmaxf(accS[0][2], accS[0][3])),
                         fmaxf(fmaxf(fmaxf(accS[1][0], accS[1][1]), fmaxf(accS[1][2], accS[1][3])),
                               fmaxf(fmaxf(fmaxf(accS[2][0], accS[2][1]), fmaxf(accS[2][2], accS[2][3])),
                                     fmaxf(fmaxf(accS[3][0], accS[3][1]), fmaxf(accS[3][2], accS[3][3])))));
        mx = fmaxf(mx, __shfl_xor(mx, 16, 64));
        mx = fmaxf(mx, __shfl_xor(mx, 32, 64));
        float nm = fmaxf(m_st, mx * scale);
        float alpha = __expf(m_st - nm);
        m_st = nm;

        float p[4][4];
        float rs = 0.f;
        #pragma unroll
        for (int t = 0; t < 4; t++)
            #pragma unroll
            for (int r = 0; r < 4; r++) {
                p[t][r] = __expf(accS[t][r] * scale - nm);
                rs += p[t][r];
            }
        rs += __shfl_xor(rs, 16, 64);
        rs += __shfl_xor(rs, 32, 64);
        l_st = l_st * alpha + rs;

        // pack P^T to bf16 pairs: uA[t]=keys(4q'+0,1), uB[t]=keys(4q'+2,3) for q'=quad
        unsigned uA[4], uB[4];
        #pragma unroll
        for (int t = 0; t < 4; t++) {
            uA[t] = (unsigned)f2bf(p[t][0]) | ((unsigned)f2bf(p[t][1]) << 16);
            uB[t] = (unsigned)f2bf(p[t][2]) | ((unsigned)f2bf(p[t][3]) << 16);
        }

        // rescale accO by alpha (transposed to accO rows q = 4*quad+r)
        float al[4];
        #pragma unroll
        for (int r = 0; r < 4; r++) al[r] = __shfl(alpha, 4 * quad + r, 64);
        #pragma unroll
        for (int nt = 0; nt < 8; nt++)
            #pragma unroll
            for (int r = 0; r < 4; r++) accO[nt][r] *= al[r];

        // O += P V : build pf (A-op: lane holds P[q=ln][k=h*32+8*quad+j]) via shfl
        #pragma unroll
        for (int h = 0; h < 2; h++) {
            unsigned a0 = (unsigned)__shfl((int)uA[2 * h], srcA, 64);
            unsigned a1 = (unsigned)__shfl((int)uA[2 * h + 1], srcA, 64);
            unsigned b0 = (unsigned)__shfl((int)uB[2 * h], srcA, 64);
            unsigned b1 = (unsigned)__shfl((int)uB[2 * h + 1], srcA, 64);
            unsigned c0 = (unsigned)__shfl((int)uA[2 * h], srcB, 64);
            unsigned c1 = (unsigned)__shfl((int)uA[2 * h + 1], srcB, 64);
            unsigned d0 = (unsigned)__shfl((int)uB[2 * h], srcB, 64);
            unsigned d1 = (unsigned)__shfl((int)uB[2 * h + 1], srcB, 64);
            union { unsigned w4[4]; bf16x8 v; } pu;
            pu.w4[0] = hi ? a1 : a0;
            pu.w4[1] = hi ? b1 : b0;
            pu.w4[2] = hi ? c1 : c0;
            pu.w4[3] = hi ? d1 : d0;
            bf16x8 pf = pu.v;
            #pragma unroll
            for (int nt = 0; nt < 8; nt++) {
                bf16x8 vf = *(const bf16x8*)(V + (nt * 16 + ln) * 64 +
                                             (((4 * h + quad) ^ (ln & 7)) * 8));
                accO[nt] = __builtin_amdgcn_mfma_f32_16x16x32_bf16(pf, vf, accO[nt], 0, 0, 0);
            }
        }

        if (nkb < 0) break;
        __builtin_amdgcn_s_barrier();           // all reads of bufc done -> reusable
        bufc ^= 1;
    }

    // epilogue: attn_bf[row][ch*128 + col] = O / l  (l transposed to rows q=4*quad+r)
    float linv = 1.0f / fmaxf(l_st, 1e-20f);
    float inv[4];
    #pragma unroll
    for (int r = 0; r < 4; r++) inv[r] = __shfl(linv, 4 * quad + r, 64);
    #pragma unroll
    for (int nt = 0; nt < 8; nt++)
        #pragma unroll
        for (int r = 0; r < 4; r++)
            attn_bf[(size_t)(rowbase + 4 * quad + r) * 256 + ch * 128 + nt * 16 + ln]
                = f2bf(accO[nt][r] * inv[r]);
}

// ---------------- out projection, 128x128 tile (grid 128x2 = 256 blocks) ----------------
__global__ __launch_bounds__(256, 3) void out_gemm(
    const u16* __restrict__ A, const u16* __restrict__ W, const float* __restrict__ bias,
    float* __restrict__ out) {
    __shared__ __align__(16) u16 As[128 * 64];
    __shared__ __align__(16) u16 Bs[128 * 64];
    int m0 = blockIdx.x * 128, n0 = blockIdx.y * 128;
    int tid = threadIdx.x, lane = tid & 63, w = tid >> 6;
    int ln = lane & 15, quad = lane >> 4;
    int rw = (w >> 1) * 64, cw = (w & 1) * 64;
    int lr8 = lane >> 3, lc = lane & 7;
    f32x4 acc[4][4] = {};
    for (int kk = 0; kk < 256; kk += 64) {
        __syncthreads();
        #pragma unroll
        for (int j = 0; j < 4; j++) {
            int r0 = w * 32 + j * 8, r = r0 + lr8;
            gload16(A + (size_t)(m0 + r) * 256 + kk + ((lc ^ (r & 7)) * 8), As + r0 * 64 + lane * 8);
            gload16(W + (size_t)(n0 + r) * 256 + kk + ((lc ^ (r & 7)) * 8), Bs + r0 * 64 + lane * 8);
        }
        __syncthreads();
        #pragma unroll
        for (int s = 0; s < 2; s++) {
            bf16x8 af[4], bfr[4];
            #pragma unroll
            for (int i = 0; i < 4; i++) {
                int R = rw + i * 16 + ln;
                af[i] = *(const bf16x8*)(As + R * 64 + ((4 * s + quad) ^ (ln & 7)) * 8);
            }
            #pragma unroll
            for (int t = 0; t < 4; t++) {
                int R = cw + t * 16 + ln;
                bfr[t] = *(const bf16x8*)(Bs + R * 64 + ((4 * s + quad) ^ (ln & 7)) * 8);
            }
            #pragma unroll
            for (int i = 0; i < 4; i++)
                #pragma unroll
                for (int t = 0; t < 4; t++)
                    acc[i][t] = __builtin_amdgcn_mfma_f32_16x16x32_bf16(af[i], bfr[t], acc[i][t], 0, 0, 0);
        }
    }
    // epilogue: col halves are block-uniform (n0 in {0,128})
    const size_t half = (size_t)M_TOT * 128;
    #pragma unroll
    for (int i = 0; i < 4; i++) {
        int row0 = m0 + rw + i * 16 + 4 * quad;
        #pragma unroll
        for (int t = 0; t < 4; t++) {
            int col = n0 + cw + t * 16 + ln;
            float bv = bias[col];
            float* base = (col < 128) ? (out + col) : (out + half + (col - 128));
            #pragma unroll
            for (int r = 0; r < 4; r++)
                base[(size_t)(row0 + r) * 128] = acc[i][t][r] + bv;
        }
    }
}

extern "C" void kernel_launch(void* const* d_in, const int* in_sizes, int n_in,
                              void* d_out, int out_size, void* d_ws, size_t ws_size,
                              hipStream_t stream) {
    char* ws = (char*)d_ws;
    u16* x_bf    = (u16*)ws;                          // 16384*768  = 25.2 MB
    u16* qk_buf  = x_bf + (size_t)M_TOT * 768;        // 16384*512  = 16.8 MB
    u16* vt_buf  = qk_buf + (size_t)M_TOT * 512;      // 1024*4096  =  8.4 MB
    u16* attn_bf = vt_buf + (size_t)1024 * SEQ_L;     // 16384*256  =  8.4 MB
    u16* Wqkv_bf = attn_bf + (size_t)M_TOT * 256;     // 589824
    u16* Wout_bf = Wqkv_bf + 589824;                  // 65536
    unsigned long long* bmap = (unsigned long long*)(Wout_bf + 65536);   // 64 x u64

    hipLaunchKernelGGL(prep_all, dim3(6480), dim3(256), 0, stream,
                       (const float*)d_in[0], (const float*)d_in[1], (const float*)d_in[2],
                       (const float*)d_in[3], (const float*)d_in[4], (const float*)d_in[5],
                       (const float*)d_in[6], (const float*)d_in[8], d_in[10],
                       x_bf, Wqkv_bf, Wout_bf, bmap);
    hipLaunchKernelGGL(qkv_gemm, dim3(128, 6), dim3(256), 0, stream,
                       x_bf, Wqkv_bf, (const float*)d_in[7], qk_buf, vt_buf);
    hipLaunchKernelGGL(attn_sparse, dim3(512), dim3(256), 0, stream,
                       qk_buf, vt_buf, bmap, attn_bf);
    hipLaunchKernelGGL(out_gemm, dim3(128, 2), dim3(256), 0, stream,
                       attn_bf, Wout_bf, (const float*)d_in[9], (float*)d_out);
}